// Round 1
// baseline (636.951 us; speedup 1.0000x reference)
//
#include <hip/hip_runtime.h>
#include <hip/hip_bf16.h>
#include <math.h>

#define HID  128
#define FILT 128
#define NG   50
#define EPB  64   // edges per tile

typedef __attribute__((ext_vector_type(8))) short bf16x8;
typedef __attribute__((ext_vector_type(4))) float f32x4;
typedef __attribute__((ext_vector_type(4))) int   i32x4;
typedef unsigned short u16;

__device__ __forceinline__ u16 f2bf(float f) {
    __hip_bfloat16 h = __float2bfloat16(f);
    return *reinterpret_cast<u16*>(&h);
}

__device__ __forceinline__ float sspf(float v) {
    // softplus(v) - ln2
    float sp = (v > 15.f) ? v : log1pf(__expf(v));
    return sp - 0.69314718056f;
}

// ---------------------------------------------------------------------------
// prep: transpose + bf16-convert edge-MLP weights.
// w1T: [128 n][64 k] (k>=50 zero-padded), w2T: [128 n][128 k]
// ---------------------------------------------------------------------------
__global__ void prep_w(const float* __restrict__ w1, const float* __restrict__ w2,
                       u16* __restrict__ w1T, u16* __restrict__ w2T)
{
    int t = blockIdx.x * 256 + threadIdx.x;
    if (t < 128 * 64) {
        int n = t >> 6, k = t & 63;
        w1T[t] = (k < NG) ? f2bf(w1[k * FILT + n]) : (u16)0;
    }
    if (t < 128 * 128) {
        int n = t >> 7, k = t & 127;
        w2T[t] = f2bf(w2[k * FILT + n]);
    }
}

// ---------------------------------------------------------------------------
// fp32 node GEMM: C[r][c] = act( sum_k A[r][k]*Wg[k][c] + bias[c] )
// ACT: 0 = none, 1 = shifted softplus
// ---------------------------------------------------------------------------
template<int ACT>
__global__ __launch_bounds__(256) void node_gemm(
    const float* __restrict__ A, const float* __restrict__ Wg,
    const float* __restrict__ bias, float* __restrict__ C, int nrows)
{
    __shared__ float sA[32][128];
    const int tid = threadIdx.x;
    const int tx = tid & 31;     // 32 col groups of 4
    const int ty = tid >> 5;     // 8 row groups of 4
    const int r0 = blockIdx.x * 32;

    for (int i = tid; i < 32 * 128; i += 256) {
        int r = i >> 7, k = i & 127;
        sA[r][k] = (r0 + r < nrows) ? A[(r0 + r) * HID + k] : 0.f;
    }
    __syncthreads();

    f32x4 acc[4];
#pragma unroll
    for (int i = 0; i < 4; ++i) acc[i] = (f32x4){0.f, 0.f, 0.f, 0.f};

#pragma unroll 4
    for (int k = 0; k < 128; ++k) {
        f32x4 wv = *reinterpret_cast<const f32x4*>(Wg + k * FILT + tx * 4);
        float a0 = sA[ty * 4 + 0][k];
        float a1 = sA[ty * 4 + 1][k];
        float a2 = sA[ty * 4 + 2][k];
        float a3 = sA[ty * 4 + 3][k];
        acc[0] += a0 * wv; acc[1] += a1 * wv; acc[2] += a2 * wv; acc[3] += a3 * wv;
    }

    f32x4 bv = (f32x4){0.f, 0.f, 0.f, 0.f};
    if (bias) bv = *reinterpret_cast<const f32x4*>(bias + tx * 4);
#pragma unroll
    for (int i = 0; i < 4; ++i) {
        int row = r0 + ty * 4 + i;
        if (row < nrows) {
            f32x4 o = acc[i] + bv;
            if (ACT) { o[0] = sspf(o[0]); o[1] = sspf(o[1]); o[2] = sspf(o[2]); o[3] = sspf(o[3]); }
            *reinterpret_cast<f32x4*>(C + row * FILT + tx * 4) = o;
        }
    }
}

// ---------------------------------------------------------------------------
// fused edge kernel: distances -> gaussians -> MLP (bf16 MFMA) -> cutoff ->
// gather x[col] -> atomicAdd into agg[row].
// persistent blocks; 4 waves/block, each wave owns 32 filter cols; 64 edges/tile.
// ---------------------------------------------------------------------------
__global__ __launch_bounds__(256, 3) void edge_kernel(
    const float* __restrict__ pos,
    const int*   __restrict__ eidx,   // [2*E]: row = eidx[e], col = eidx[E+e]
    const u16*   __restrict__ w1T,    // [128][64] bf16
    const u16*   __restrict__ w2T,    // [128][128] bf16
    const float* __restrict__ b1,
    const float* __restrict__ b2,
    const float* __restrict__ x,      // [N][128] f32
    float*       __restrict__ agg,    // [N][128] f32 (pre-zeroed)
    int E)
{
    __shared__ u16  sw2[FILT * FILT];   // [n][k] bf16, XOR-swizzled
    __shared__ u16  sU[EPB * FILT];     // union: sA [64][64] then sT [64][128]
    __shared__ float sC[EPB];
    __shared__ float sd[EPB];
    __shared__ int   srow[EPB];
    __shared__ int   scol[EPB];
    __shared__ float sb1[FILT];
    __shared__ float sb2[FILT];

    const int tid  = threadIdx.x;
    const int lane = tid & 63;
    const int wv   = tid >> 6;      // wave 0..3 -> cols [32*wv, 32*wv+32)
    const int l15  = lane & 15;
    const int l4   = lane >> 4;     // 0..3

    // stage swizzled w2 once per (persistent) block
    for (int c = tid; c < FILT * 16; c += 256) {       // 16B chunks
        int n = c >> 4, kb = c & 15;
        i32x4 v = *reinterpret_cast<const i32x4*>(w2T + n * FILT + kb * 8);
        int byteoff = n * 256 + ((kb * 16) ^ ((n & 7) << 4));
        *reinterpret_cast<i32x4*>(reinterpret_cast<char*>(sw2) + byteoff) = v;
    }
    if (tid < FILT) { sb1[tid] = b1[tid]; sb2[tid] = b2[tid]; }
    __syncthreads();

    const float GSTEP = 10.0f / 49.0f;
    const float COEFF = -0.5f / (GSTEP * GSTEP);
    const int ntiles = (E + EPB - 1) / EPB;

    for (int tile = blockIdx.x; tile < ntiles; tile += gridDim.x) {
        const int e0 = tile * EPB;

        // --- phase 1: per-edge scalars --------------------------------------
        if (tid < EPB) {
            int e = e0 + tid;
            int r = 0, c = 0; float d = 0.f, Cf = 0.f;
            if (e < E) {
                r = eidx[e]; c = eidx[E + e];
                float dx = pos[3 * r + 0] - pos[3 * c + 0];
                float dy = pos[3 * r + 1] - pos[3 * c + 1];
                float dz = pos[3 * r + 2] - pos[3 * c + 2];
                d  = sqrtf(dx * dx + dy * dy + dz * dz);
                Cf = 0.5f * (cosf(d * 0.3141592653589793f) + 1.0f);  // pi/CUTOFF
            }
            srow[tid] = r; scol[tid] = c; sd[tid] = d; sC[tid] = Cf;  // Cf=0 kills OOB edges
        }
        __syncthreads();

        // --- phase 2: gaussian tile sA [64 e][64 g] bf16, swizzled ----------
        for (int i = tid; i < EPB * 64; i += 256) {
            int e = i >> 6, g = i & 63;
            float v = 0.f;
            if (g < NG) { float t = sd[e] - (float)g * GSTEP; v = __expf(COEFF * t * t); }
            int byteoff = e * 128 + ((g * 2) ^ ((e & 7) << 4));
            *reinterpret_cast<u16*>(reinterpret_cast<char*>(sU) + byteoff) = f2bf(v);
        }
        __syncthreads();

        // --- GEMM1: t1 = ssp(sA @ w1 + b1), K=64 ----------------------------
        f32x4 acc1[4][2];
#pragma unroll
        for (int mt = 0; mt < 4; ++mt)
#pragma unroll
            for (int nt = 0; nt < 2; ++nt) acc1[mt][nt] = (f32x4){0.f, 0.f, 0.f, 0.f};

        bf16x8 bw1[2][2];
#pragma unroll
        for (int nt = 0; nt < 2; ++nt)
#pragma unroll
            for (int s = 0; s < 2; ++s) {
                int n = wv * 32 + nt * 16 + l15;
                bw1[nt][s] = *reinterpret_cast<const bf16x8*>(w1T + n * 64 + s * 32 + l4 * 8);
            }
#pragma unroll
        for (int mt = 0; mt < 4; ++mt) {
#pragma unroll
            for (int s = 0; s < 2; ++s) {
                int e = mt * 16 + l15;
                int byteoff = e * 128 + (((s * 64 + l4 * 16)) ^ ((e & 7) << 4));
                bf16x8 af = *reinterpret_cast<const bf16x8*>(reinterpret_cast<char*>(sU) + byteoff);
                acc1[mt][0] = __builtin_amdgcn_mfma_f32_16x16x32_bf16(af, bw1[0][s], acc1[mt][0], 0, 0, 0);
                acc1[mt][1] = __builtin_amdgcn_mfma_f32_16x16x32_bf16(af, bw1[1][s], acc1[mt][1], 0, 0, 0);
            }
        }
        __syncthreads();   // all sA reads done before sT overwrites the union

        // ssp + write t1 tile sT [64 e][128 k] bf16, swizzled
#pragma unroll
        for (int mt = 0; mt < 4; ++mt)
#pragma unroll
            for (int nt = 0; nt < 2; ++nt)
#pragma unroll
                for (int r = 0; r < 4; ++r) {
                    int m = mt * 16 + l4 * 4 + r;            // edge row
                    int n = wv * 32 + nt * 16 + l15;         // filter col
                    float v = sspf(acc1[mt][nt][r] + sb1[n]);
                    int byteoff = m * 256 + ((n * 2) ^ ((m & 7) << 4));
                    *reinterpret_cast<u16*>(reinterpret_cast<char*>(sU) + byteoff) = f2bf(v);
                }
        __syncthreads();

        // --- GEMM2: W = t1 @ w2 + b2, K=128 ---------------------------------
        f32x4 acc2[4][2];
#pragma unroll
        for (int mt = 0; mt < 4; ++mt)
#pragma unroll
            for (int nt = 0; nt < 2; ++nt) acc2[mt][nt] = (f32x4){0.f, 0.f, 0.f, 0.f};

#pragma unroll
        for (int s = 0; s < 4; ++s) {
            bf16x8 bw2[2];
#pragma unroll
            for (int nt = 0; nt < 2; ++nt) {
                int n = wv * 32 + nt * 16 + l15;
                int byteoff = n * 256 + (((s * 64 + l4 * 16)) ^ ((n & 7) << 4));
                bw2[nt] = *reinterpret_cast<const bf16x8*>(reinterpret_cast<char*>(sw2) + byteoff);
            }
#pragma unroll
            for (int mt = 0; mt < 4; ++mt) {
                int e = mt * 16 + l15;
                int byteoff = e * 256 + (((s * 64 + l4 * 16)) ^ ((e & 7) << 4));
                bf16x8 af = *reinterpret_cast<const bf16x8*>(reinterpret_cast<char*>(sU) + byteoff);
                acc2[mt][0] = __builtin_amdgcn_mfma_f32_16x16x32_bf16(af, bw2[0], acc2[mt][0], 0, 0, 0);
                acc2[mt][1] = __builtin_amdgcn_mfma_f32_16x16x32_bf16(af, bw2[1], acc2[mt][1], 0, 0, 0);
            }
        }

        // --- epilogue: W *= C; msg = x[col]*W; scatter ----------------------
#pragma unroll
        for (int mt = 0; mt < 4; ++mt)
#pragma unroll
            for (int nt = 0; nt < 2; ++nt) {
                int n = wv * 32 + nt * 16 + l15;
                float bb = sb2[n];
#pragma unroll
                for (int r = 0; r < 4; ++r) {
                    int el = mt * 16 + l4 * 4 + r;
                    float Wv = (acc2[mt][nt][r] + bb) * sC[el];
                    float xv = x[scol[el] * HID + n];
                    atomicAdd(agg + srow[el] * HID + n, Wv * xv);
                }
            }
        __syncthreads();   // protect sU/scalars before next tile
    }
}

// ---------------------------------------------------------------------------
extern "C" void kernel_launch(void* const* d_in, const int* in_sizes, int n_in,
                              void* d_out, int out_size, void* d_ws, size_t ws_size,
                              hipStream_t stream)
{
    const float* h    = (const float*)d_in[0];
    const float* pos  = (const float*)d_in[1];
    const int*   eidx = (const int*)  d_in[2];
    const float* w1   = (const float*)d_in[3];
    const float* b1   = (const float*)d_in[4];
    const float* w2   = (const float*)d_in[5];
    const float* b2   = (const float*)d_in[6];
    const float* lin1 = (const float*)d_in[7];
    const float* lin2 = (const float*)d_in[8];
    const float* l2b  = (const float*)d_in[9];
    const float* linw = (const float*)d_in[10];
    const float* linb = (const float*)d_in[11];

    const int N = in_sizes[0] / HID;
    const int E = in_sizes[2] / 2;

    float* xbuf = (float*)d_ws;                       // [N][128] f32
    size_t xbytes = (size_t)N * HID * sizeof(float);
    u16* w1T = (u16*)((char*)d_ws + xbytes);          // [128][64] bf16
    u16* w2T = w1T + 128 * 64;                        // [128][128] bf16

    float* agg = (float*)d_out;                       // reuse output as agg

    hipMemsetAsync(d_out, 0, (size_t)out_size * sizeof(float), stream);
    prep_w<<<64, 256, 0, stream>>>(w1, w2, w1T, w2T);

    // x = h @ lin1
    node_gemm<0><<<(N + 31) / 32, 256, 0, stream>>>(h, lin1, nullptr, xbuf, N);

    // edge pipeline + scatter into agg (= d_out)
    edge_kernel<<<768, 256, 0, stream>>>(pos, eidx, w1T, w2T, b1, b2, xbuf, agg, E);

    // tmp = ssp(agg @ lin2 + l2b)   (reuse xbuf; x is dead now)
    node_gemm<1><<<(N + 31) / 32, 256, 0, stream>>>(agg, lin2, l2b, xbuf, N);

    // out = tmp @ lin_w + lin_b
    node_gemm<0><<<(N + 31) / 32, 256, 0, stream>>>(xbuf, linw, linb, (float*)d_out, N);
}